// Round 11
// baseline (46.109 us; speedup 1.0000x reference)
//
#include <hip/hip_runtime.h>
#include <hip/hip_bf16.h>
#include <math.h>

#define BB 4
#define PP 4096
#define HH 256
#define INV_T (1.0f/0.07f)
#define JSPLIT 8
#define NTILES (PP/16)
#define TILE_BYTES 8192
#define RBROWS 128               // rows per k_loss block (2 x 16 per wave)
#define NRB (PP/RBROWS)          // 32 row-groups max
#define D2GRID (NRB*32)          // 1024: L = rb*32 + b*8 + chunk

typedef __attribute__((ext_vector_type(8))) short bf16x8;
typedef __attribute__((ext_vector_type(4))) float f32x4;

#define WAITVM(n) asm volatile("s_waitcnt vmcnt(" #n ")" ::: "memory")

__device__ __forceinline__ unsigned short f2bf(float x){
  union { float f; unsigned u; } v; v.f = x;
  unsigned r = v.u + 0x7FFFu + ((v.u >> 16) & 1u);   // RNE
  return (unsigned short)(r >> 16);
}

__device__ __forceinline__ void gload_lds16(const void* g, void* l){
  __builtin_amdgcn_global_load_lds(
      (const __attribute__((address_space(1))) unsigned int*)g,
      (__attribute__((address_space(3))) unsigned int*)l, 16, 0, 0);
}

// ---------------- D0: label scan -> posIdx, negRank, meta ----------------
__global__ void k_scan(const int* __restrict__ labels, int* __restrict__ meta,
                       int* __restrict__ posIdx, int* __restrict__ negRank){
  int b = blockIdx.x;
  const int* lab = labels + b * PP;
  __shared__ int wP[4], wN[4], wV[4];
  __shared__ int basePos, baseNeg, baseVal;
  int tid = threadIdx.x, wave = tid >> 6, lane = tid & 63;
  if (tid == 0){ basePos = 0; baseNeg = 0; baseVal = 0; }
  __syncthreads();
  for (int c = 0; c < PP; c += 256){
    int p = c + tid;
    int l = lab[p];
    bool isP = (l == 1), isN = (l == 0), isV = (l != -100);
    unsigned long long bP = __ballot(isP), bN = __ballot(isN), bV = __ballot(isV);
    unsigned long long lt = (1ull << lane) - 1ull;
    if (lane == 0){ wP[wave] = __popcll(bP); wN[wave] = __popcll(bN); wV[wave] = __popcll(bV); }
    __syncthreads();
    int offP = 0, offN = 0;
    for (int w = 0; w < wave; w++){ offP += wP[w]; offN += wN[w]; }
    if (isP) posIdx[b*PP + basePos + offP + __popcll(bP & lt)] = p;
    if (isN) negRank[b*PP + p] = baseNeg + offN + __popcll(bN & lt);
    __syncthreads();
    if (tid == 0){
      basePos += wP[0]+wP[1]+wP[2]+wP[3];
      baseNeg += wN[0]+wN[1]+wN[2]+wN[3];
      baseVal += wV[0]+wV[1]+wV[2]+wV[3];
    }
    __syncthreads();
  }
  if (tid == 0){
    int Np = basePos, Nn = baseNeg, nv = baseVal;
    meta[b*4+0] = Np; meta[b*4+1] = Nn;
    meta[b*4+2] = (nv >= 2 && Np > 0 && Nn > 0) ? 1 : 0;
    meta[b*4+3] = nv;
  }
}

// ---------------- D1: normalize; pos -> Gn natural + diagN; neg -> EnF compacted frag-ready ----------------
__global__ void k_norm(const float* __restrict__ greek, const float* __restrict__ english,
                       const int* __restrict__ labels, const int* __restrict__ negRank,
                       unsigned short* __restrict__ Gn, unsigned short* __restrict__ EnF,
                       float* __restrict__ diagN){
  int tid = threadIdx.x, wave = tid >> 6, lane = tid & 63;
  int u = blockIdx.x * 4 + wave;           // [0, BB*PP)
  int lab = labels[u];
  if (lab == -100) return;                 // wave-uniform exit
  int b = u >> 12;
  size_t base = (size_t)u * HH + lane * 4;
  if (lab == 1){
    float4 g4 = *reinterpret_cast<const float4*>(greek + base);
    float4 e4 = *reinterpret_cast<const float4*>(english + base);
    float ag = g4.x*g4.x + g4.y*g4.y + g4.z*g4.z + g4.w*g4.w;
    float ae = e4.x*e4.x + e4.y*e4.y + e4.z*e4.z + e4.w*e4.w;
    float ad = g4.x*e4.x + g4.y*e4.y + g4.z*e4.z + g4.w*e4.w;
    #pragma unroll
    for (int off = 32; off; off >>= 1){
      ag += __shfl_xor(ag, off); ae += __shfl_xor(ae, off); ad += __shfl_xor(ad, off);
    }
    float gs = 1.0f / fmaxf(sqrtf(ag), 1e-12f);
    float es = 1.0f / fmaxf(sqrtf(ae), 1e-12f);
    ushort4 go; go.x=f2bf(g4.x*gs); go.y=f2bf(g4.y*gs); go.z=f2bf(g4.z*gs); go.w=f2bf(g4.w*gs);
    *reinterpret_cast<ushort4*>(Gn + (size_t)u*HH + lane*4) = go;
    if (lane == 0) diagN[u] = ad * gs * es;
  } else {   // negative -> fragment-ready tile at COMPACTED index
    float4 e4 = *reinterpret_cast<const float4*>(english + base);
    float ae = e4.x*e4.x + e4.y*e4.y + e4.z*e4.z + e4.w*e4.w;
    #pragma unroll
    for (int off = 32; off; off >>= 1) ae += __shfl_xor(ae, off);
    float es = 1.0f / fmaxf(sqrtf(ae), 1e-12f);
    unsigned u0 = (unsigned)f2bf(e4.x*es) | ((unsigned)f2bf(e4.y*es) << 16);
    unsigned u1 = (unsigned)f2bf(e4.z*es) | ((unsigned)f2bf(e4.w*es) << 16);
    unsigned o0 = __shfl_xor(u0, 1), o1 = __shfl_xor(u1, 1);
    int rank = negRank[u];
    char* dst = (char*)EnF + ((size_t)b*NTILES + (rank>>4))*TILE_BYTES
              + (lane>>3)*1024 + (((rank&15) + ((lane>>1)&3)*16) << 4);
    if (!(lane & 1)) *(uint4*)dst = make_uint4(u0, u1, o0, o1);
  }
}

// ---------------- D2: MFMA exp-sums, compacted tiles, 128 rows/block ----------------
// L = rb*32 + b*8 + chunk (chunk = L%8 -> B-slice XCD locality). Verified triple-buffer
// counted-vmcnt pipeline; each wave owns TWO 16-row A-sets (halves B re-staging).
__global__ void __launch_bounds__(256, 4)
k_loss(const unsigned short* __restrict__ Gn, const unsigned short* __restrict__ EnF,
       const int* __restrict__ posIdx, const int* __restrict__ meta,
       float* __restrict__ Spart){
  int L = blockIdx.x;
  int rb = L >> 5, b = (L >> 3) & 3, chunk = L & 7;
  int tid = threadIdx.x, wave = tid >> 6, lane = tid & 63;
  int lo16 = lane & 15, hi4 = lane >> 4;
  int Np = meta[b*4+0], Nn = meta[b*4+1], ok = meta[b*4+2];
  int i0 = rb * RBROWS;
  if (!ok || i0 >= Np) return;

  int NT = (Nn + 15) >> 4;
  int TPC = (NT + JSPLIT - 1) / JSPLIT;
  int t0 = chunk * TPC, t1 = min(NT, t0 + TPC);

  __shared__ __align__(16) char Bs[3][TILE_BYTES];   // 24 KB triple buffer

  // two A fragment sets (one-time per-lane gather)
  int iw0 = i0 + wave*16;
  int iw1 = iw0 + 64;
  int pr0 = posIdx[b*PP + min(iw0 + lo16, Np-1)];
  int pr1 = posIdx[b*PP + min(iw1 + lo16, Np-1)];
  const char* Ab0 = (const char*)Gn + ((size_t)b*PP + pr0)*(HH*2) + hi4*16;
  const char* Ab1 = (const char*)Gn + ((size_t)b*PP + pr1)*(HH*2) + hi4*16;
  bf16x8 a0[8], a1[8];
  #pragma unroll
  for (int kk = 0; kk < 8; kk++){
    a0[kk] = *reinterpret_cast<const bf16x8*>(Ab0 + kk*64);
    a1[kk] = *reinterpret_cast<const bf16x8*>(Ab1 + kk*64);
  }

  const char* EFb = (const char*)EnF + (size_t)b * NTILES * TILE_BYTES;
  auto STAGE = [&](int t, int buf){
    const char* src = EFb + (size_t)t*TILE_BYTES + (wave << 11) + (lane << 4);
    char* d = &Bs[buf][wave << 11];                 // linear LDS dest (+lane*16 in HW)
    gload_lds16(src, d);
    gload_lds16(src + 1024, d + 1024);
  };

  float s0[4] = {0.f,0.f,0.f,0.f}, s1[4] = {0.f,0.f,0.f,0.f};
  if (t0 < t1){
    STAGE(t0, 0);
    if (t0 + 1 < t1) STAGE(t0+1, 1);
    int cur = 0;
    for (int t = t0; t < t1; t++){
      if (t + 1 < t1) WAITVM(2);   // drains tile t (first iter: also A-loads)
      else            WAITVM(0);
      __builtin_amdgcn_s_barrier();
      __builtin_amdgcn_sched_barrier(0);
      if (t + 2 < t1){
        int nbuf = cur + 2; if (nbuf >= 3) nbuf -= 3;
        STAGE(t+2, nbuf);
      }
      const char* Bt = &Bs[cur][0];
      f32x4 c0 = {0.f,0.f,0.f,0.f}, c1 = {0.f,0.f,0.f,0.f};
      #pragma unroll
      for (int kk = 0; kk < 8; kk++){
        bf16x8 bv = *reinterpret_cast<const bf16x8*>(Bt + kk*1024 + (lane << 4));
        c0 = __builtin_amdgcn_mfma_f32_16x16x32_bf16(a0[kk], bv, c0, 0, 0, 0);
        c1 = __builtin_amdgcn_mfma_f32_16x16x32_bf16(a1[kk], bv, c1, 0, 0, 0);
      }
      bool cok = (t*16 + lo16) < Nn;
      #pragma unroll
      for (int r = 0; r < 4; r++){
        s0[r] += cok ? __expf(c0[r] * INV_T) : 0.0f;
        s1[r] += cok ? __expf(c1[r] * INV_T) : 0.0f;
      }
      cur = (cur == 2) ? 0 : cur + 1;
    }
  }

  // reduce across the 16 col-lanes; D layout: col=lane&15, row=hi4*4+r
  #pragma unroll
  for (int off = 1; off < 16; off <<= 1){
    #pragma unroll
    for (int r = 0; r < 4; r++){
      s0[r] += __shfl_xor(s0[r], off);
      s1[r] += __shfl_xor(s1[r], off);
    }
  }
  if (lo16 == 0){
    #pragma unroll
    for (int r = 0; r < 4; r++){
      int ia = iw0 + hi4*4 + r;
      int ib2 = iw1 + hi4*4 + r;
      Spart[(((size_t)b*PP + ia) << 3) + chunk] = s0[r];
      Spart[(((size_t)b*PP + ib2) << 3) + chunk] = s1[r];
    }
  }
}

// ---------------- D3: fold partials -> per-row loss -> mean ----------------
__global__ void k_final(const float* __restrict__ Spart, const float* __restrict__ diagN,
                        const int* __restrict__ posIdx, const int* __restrict__ meta,
                        float* __restrict__ out){
  __shared__ float lds[16];
  int tid = threadIdx.x;
  int np[BB], okk[BB];
  #pragma unroll
  for (int b = 0; b < BB; b++){ np[b] = meta[b*4+0]; okk[b] = meta[b*4+2]; }
  float tot = 0.0f;
  for (int idx = tid; idx < BB*PP; idx += 1024){
    int b = idx >> 12, i = idx & (PP-1);
    if (!okk[b] || i >= np[b]) continue;
    const float4* p = reinterpret_cast<const float4*>(Spart + ((size_t)idx << 3));
    float4 p0 = p[0], p1 = p[1];
    float S = ((p0.x+p0.y)+(p0.z+p0.w)) + ((p1.x+p1.y)+(p1.z+p1.w));
    float dl = diagN[b*PP + posIdx[idx]] * INV_T;
    tot += logf(S + __expf(dl)) - dl;
  }
  #pragma unroll
  for (int off = 32; off; off >>= 1) tot += __shfl_xor(tot, off);
  int wave = tid >> 6;
  if ((tid & 63) == 0) lds[wave] = tot;
  __syncthreads();
  if (tid == 0){
    float total = 0.0f;
    #pragma unroll
    for (int w = 0; w < 16; w++) total += lds[w];
    int count = 0;
    #pragma unroll
    for (int b = 0; b < BB; b++) if (okk[b]) count += np[b];
    out[0] = (count == 0) ? 0.0f : total / (float)count;
  }
}

extern "C" void kernel_launch(void* const* d_in, const int* in_sizes, int n_in,
                              void* d_out, int out_size, void* d_ws, size_t ws_size,
                              hipStream_t stream){
  const float* greek   = (const float*)d_in[0];
  const float* english = (const float*)d_in[1];
  const int*   labels  = (const int*)d_in[2];
  float* out = (float*)d_out;

  char* ws = (char*)d_ws;
  size_t off = 0;
  unsigned short* Gn   = (unsigned short*)(ws + off); off += (size_t)BB*PP*HH*2;          // 8MB
  unsigned short* EnF  = (unsigned short*)(ws + off); off += (size_t)BB*NTILES*TILE_BYTES;// 8MB
  float* Spart      = (float*)(ws + off); off += (size_t)BB*PP*8*sizeof(float);           // 512KB
  float* diagN      = (float*)(ws + off); off += (size_t)BB*PP*sizeof(float);             // 64KB
  int*   posIdx     = (int*)(ws + off);   off += (size_t)BB*PP*sizeof(int);               // 64KB
  int*   negRank    = (int*)(ws + off);   off += (size_t)BB*PP*sizeof(int);               // 64KB
  int*   meta       = (int*)(ws + off);   off += 64;

  k_scan<<<BB, 256, 0, stream>>>(labels, meta, posIdx, negRank);
  k_norm<<<BB*PP/4, 256, 0, stream>>>(greek, english, labels, negRank, Gn, EnF, diagN);
  k_loss<<<D2GRID, 256, 0, stream>>>(Gn, EnF, posIdx, meta, Spart);
  k_final<<<1, 1024, 0, stream>>>(Spart, diagN, posIdx, meta, out);
}

// Round 12
// 39.356 us; speedup vs baseline: 1.1716x; 1.1716x over previous
//
#include <hip/hip_runtime.h>
#include <hip/hip_bf16.h>
#include <math.h>

#define BB 4
#define PP 4096
#define HH 256
#define INV_T (1.0f/0.07f)
#define JSPLIT 8
#define NTILES (PP/16)
#define TILE_BYTES 8192

typedef __attribute__((ext_vector_type(8))) short bf16x8;
typedef __attribute__((ext_vector_type(4))) float f32x4;

#define WAITVM(n) asm volatile("s_waitcnt vmcnt(" #n ")" ::: "memory")

__device__ __forceinline__ unsigned short f2bf(float x){
  union { float f; unsigned u; } v; v.f = x;
  unsigned r = v.u + 0x7FFFu + ((v.u >> 16) & 1u);   // RNE
  return (unsigned short)(r >> 16);
}

__device__ __forceinline__ void gload_lds16(const void* g, void* l){
  __builtin_amdgcn_global_load_lds(
      (const __attribute__((address_space(1))) unsigned int*)g,
      (__attribute__((address_space(3))) unsigned int*)l, 16, 0, 0);
}

// ---------------- D0: single-pass label scan -> rank[], meta ----------------
// rank[p] = compacted index among positives (label==1) or negatives (label==0).
// 2 barriers total: counts -> 64-entry exclusive prefix -> rank writes.
__global__ void k_scan(const int* __restrict__ labels, int* __restrict__ meta,
                       int* __restrict__ rank){
  int b = blockIdx.x;
  const int* lab = labels + b * PP;
  int tid = threadIdx.x, wave = tid >> 6, lane = tid & 63;
  __shared__ int cP[64], cN[64];     // per (chunk,wave) counts, idx = c*4+wave
  __shared__ int pP[65], pN[65];     // exclusive prefixes (+ totals at [64])
  __shared__ int vtot[4];
  int myLab[16];
  int vcnt = 0;
  #pragma unroll
  for (int c = 0; c < 16; c++){
    int l = lab[c*256 + tid];
    myLab[c] = l;
    unsigned long long bP = __ballot(l == 1), bN = __ballot(l == 0);
    vcnt += (l != -100) ? 1 : 0;
    if (lane == 0){ cP[c*4 + wave] = __popcll(bP); cN[c*4 + wave] = __popcll(bN); }
  }
  #pragma unroll
  for (int off = 32; off; off >>= 1) vcnt += __shfl_xor(vcnt, off);
  if (lane == 0) vtot[wave] = vcnt;
  __syncthreads();
  if (tid < 64){
    int sp = 0, sn = 0;
    for (int k = 0; k < tid; k++){ sp += cP[k]; sn += cN[k]; }
    pP[tid] = sp; pN[tid] = sn;
    if (tid == 63){ pP[64] = sp + cP[63]; pN[64] = sn + cN[63]; }
  }
  __syncthreads();
  #pragma unroll
  for (int c = 0; c < 16; c++){
    int l = myLab[c];
    unsigned long long bP = __ballot(l == 1), bN = __ballot(l == 0);
    unsigned long long lt = (1ull << lane) - 1ull;
    int p = b*PP + c*256 + tid;
    if (l == 1)      rank[p] = pP[c*4 + wave] + __popcll(bP & lt);
    else if (l == 0) rank[p] = pN[c*4 + wave] + __popcll(bN & lt);
  }
  if (tid == 0){
    int Np = pP[64], Nn = pN[64], nv = vtot[0]+vtot[1]+vtot[2]+vtot[3];
    meta[b*4+0] = Np; meta[b*4+1] = Nn;
    meta[b*4+2] = (nv >= 2 && Np > 0 && Nn > 0) ? 1 : 0;
    meta[b*4+3] = nv;
  }
}

// ---------------- D1: normalize -> frag-ready compacted tiles ----------------
// grid 1024; block's 4 waves = 4 consecutive rows; loop over the 4 batches.
// pos -> GposF frag-ready @rank + diagC[rank]; neg -> EnegF frag-ready @rank.
__global__ void k_norm(const float* __restrict__ greek, const float* __restrict__ english,
                       const int* __restrict__ labels, const int* __restrict__ rank,
                       unsigned short* __restrict__ GposF, unsigned short* __restrict__ EnegF,
                       float* __restrict__ diagC){
  int tid = threadIdx.x, wave = tid >> 6, lane = tid & 63;
  int r0 = blockIdx.x * 4 + wave;          // row within batch, 0..4095
  for (int b = 0; b < BB; b++){
    int u = b * PP + r0;
    int lab = labels[u];
    if (lab == -100) continue;             // wave-uniform
    size_t base = (size_t)u * HH + lane * 4;
    int rk = rank[u];
    if (lab == 1){
      float4 g4 = *reinterpret_cast<const float4*>(greek + base);
      float4 e4 = *reinterpret_cast<const float4*>(english + base);
      float ag = g4.x*g4.x + g4.y*g4.y + g4.z*g4.z + g4.w*g4.w;
      float ae = e4.x*e4.x + e4.y*e4.y + e4.z*e4.z + e4.w*e4.w;
      float ad = g4.x*e4.x + g4.y*e4.y + g4.z*e4.z + g4.w*e4.w;
      #pragma unroll
      for (int off = 32; off; off >>= 1){
        ag += __shfl_xor(ag, off); ae += __shfl_xor(ae, off); ad += __shfl_xor(ad, off);
      }
      float gs = 1.0f / fmaxf(sqrtf(ag), 1e-12f);
      float es = 1.0f / fmaxf(sqrtf(ae), 1e-12f);
      unsigned u0 = (unsigned)f2bf(g4.x*gs) | ((unsigned)f2bf(g4.y*gs) << 16);
      unsigned u1 = (unsigned)f2bf(g4.z*gs) | ((unsigned)f2bf(g4.w*gs) << 16);
      unsigned o0 = __shfl_xor(u0, 1), o1 = __shfl_xor(u1, 1);
      char* dst = (char*)GposF + ((size_t)b*NTILES + (rk>>4))*TILE_BYTES
                + (lane>>3)*1024 + (((rk&15) + ((lane>>1)&3)*16) << 4);
      if (!(lane & 1)) *(uint4*)dst = make_uint4(u0, u1, o0, o1);
      if (lane == 0) diagC[b*PP + rk] = ad * gs * es;
    } else {   // negative column
      float4 e4 = *reinterpret_cast<const float4*>(english + base);
      float ae = e4.x*e4.x + e4.y*e4.y + e4.z*e4.z + e4.w*e4.w;
      #pragma unroll
      for (int off = 32; off; off >>= 1) ae += __shfl_xor(ae, off);
      float es = 1.0f / fmaxf(sqrtf(ae), 1e-12f);
      unsigned u0 = (unsigned)f2bf(e4.x*es) | ((unsigned)f2bf(e4.y*es) << 16);
      unsigned u1 = (unsigned)f2bf(e4.z*es) | ((unsigned)f2bf(e4.w*es) << 16);
      unsigned o0 = __shfl_xor(u0, 1), o1 = __shfl_xor(u1, 1);
      char* dst = (char*)EnegF + ((size_t)b*NTILES + (rk>>4))*TILE_BYTES
                + (lane>>3)*1024 + (((rk&15) + ((lane>>1)&3)*16) << 4);
      if (!(lane & 1)) *(uint4*)dst = make_uint4(u0, u1, o0, o1);
    }
  }
}

// ---------------- D2: MFMA exp-sums (r5-verified loop, contiguous frag-ready A) ----------------
// 1-D grid 2048, L = rb*32 + (b*8+chunk) -> B-slice XCD locality.
__global__ void __launch_bounds__(256, 4)
k_loss(const unsigned short* __restrict__ GposF,
       const unsigned short* __restrict__ EnegF,
       const int* __restrict__ meta,
       float* __restrict__ Spart){
  int L = blockIdx.x;
  int rb = L >> 5;
  int pair = L & 31;
  int b = pair >> 3, chunk = pair & 7;
  int Np = meta[b*4+0], Nn = meta[b*4+1], ok = meta[b*4+2];
  int i0 = rb * 64;
  if (!ok || i0 >= Np) return;
  int tid = threadIdx.x, wave = tid >> 6, lane = tid & 63;
  int lo16 = lane & 15, hi4 = lane >> 4;
  int NT = (Nn + 15) >> 4;
  int TPC = (NT + JSPLIT - 1) / JSPLIT;
  int t0 = chunk * TPC, t1 = min(NT, t0 + TPC);

  __shared__ __align__(16) char Bs[3][TILE_BYTES];   // 24 KB triple buffer

  // A fragments (one-time, fully coalesced)
  const char* AF = (const char*)GposF + ((size_t)b*NTILES + (i0 >> 4) + wave) * TILE_BYTES;
  bf16x8 a[8];
  #pragma unroll
  for (int kk = 0; kk < 8; kk++)
    a[kk] = *reinterpret_cast<const bf16x8*>(AF + kk*1024 + (lane << 4));

  const char* EF = (const char*)EnegF + (size_t)b * NTILES * TILE_BYTES;
  float s[4] = {0.f, 0.f, 0.f, 0.f};

  if (t0 < t1){
    {
      const char* src = EF + (size_t)t0*TILE_BYTES + (wave << 11) + (lane << 4);
      char* dstl = &Bs[0][wave << 11];
      gload_lds16(src, dstl);
      gload_lds16(src + 1024, dstl + 1024);
    }
    if (t0 + 1 < t1){
      const char* src = EF + (size_t)(t0+1)*TILE_BYTES + (wave << 11) + (lane << 4);
      char* dstl = &Bs[1][wave << 11];
      gload_lds16(src, dstl);
      gload_lds16(src + 1024, dstl + 1024);
    }
    int cur = 0;
    for (int t = t0; t < t1; t++){
      if (t + 1 < t1) WAITVM(2);
      else            WAITVM(0);
      __builtin_amdgcn_s_barrier();
      __builtin_amdgcn_sched_barrier(0);

      if (t + 2 < t1){
        int nb = cur + 2; if (nb >= 3) nb -= 3;
        const char* src = EF + (size_t)(t+2)*TILE_BYTES + (wave << 11) + (lane << 4);
        char* dstl = &Bs[nb][wave << 11];
        gload_lds16(src, dstl);
        gload_lds16(src + 1024, dstl + 1024);
      }

      const char* Bt = &Bs[cur][0];
      f32x4 c = {0.f, 0.f, 0.f, 0.f};
      #pragma unroll
      for (int kk = 0; kk < 8; kk++){
        bf16x8 bv = *reinterpret_cast<const bf16x8*>(Bt + kk*1024 + (lane << 4));
        c = __builtin_amdgcn_mfma_f32_16x16x32_bf16(a[kk], bv, c, 0, 0, 0);
      }
      bool cok = (t*16 + lo16) < Nn;
      #pragma unroll
      for (int r = 0; r < 4; r++)
        s[r] += cok ? __expf(c[r] * INV_T) : 0.0f;

      cur = (cur == 2) ? 0 : cur + 1;
    }
  }

  // reduce across the 16 col-lanes; D layout: col=lane&15, row=hi4*4+r
  #pragma unroll
  for (int off = 1; off < 16; off <<= 1){
    #pragma unroll
    for (int r = 0; r < 4; r++) s[r] += __shfl_xor(s[r], off);
  }
  if (lo16 == 0){
    #pragma unroll
    for (int r = 0; r < 4; r++){
      int i = i0 + wave*16 + hi4*4 + r;
      Spart[(((size_t)b*PP + i) << 3) + chunk] = s[r];
    }
  }
}

// ---------------- D3: fold partials -> per-row loss -> mean ----------------
__global__ void k_final(const float* __restrict__ Spart, const float* __restrict__ diagC,
                        const int* __restrict__ meta, float* __restrict__ out){
  __shared__ float lds[16];
  int tid = threadIdx.x;
  int np[BB], okk[BB];
  #pragma unroll
  for (int b = 0; b < BB; b++){ np[b] = meta[b*4+0]; okk[b] = meta[b*4+2]; }
  float tot = 0.0f;
  for (int idx = tid; idx < BB*PP; idx += 1024){
    int b = idx >> 12, i = idx & (PP-1);
    if (!okk[b] || i >= np[b]) continue;
    const float4* p = reinterpret_cast<const float4*>(Spart + ((size_t)idx << 3));
    float4 p0 = p[0], p1 = p[1];
    float S = ((p0.x+p0.y)+(p0.z+p0.w)) + ((p1.x+p1.y)+(p1.z+p1.w));
    float dl = diagC[idx] * INV_T;
    tot += logf(S + __expf(dl)) - dl;
  }
  #pragma unroll
  for (int off = 32; off; off >>= 1) tot += __shfl_xor(tot, off);
  int wave = tid >> 6;
  if ((tid & 63) == 0) lds[wave] = tot;
  __syncthreads();
  if (tid == 0){
    float total = 0.0f;
    #pragma unroll
    for (int w = 0; w < 16; w++) total += lds[w];
    int count = 0;
    #pragma unroll
    for (int b = 0; b < BB; b++) if (okk[b]) count += np[b];
    out[0] = (count == 0) ? 0.0f : total / (float)count;
  }
}

extern "C" void kernel_launch(void* const* d_in, const int* in_sizes, int n_in,
                              void* d_out, int out_size, void* d_ws, size_t ws_size,
                              hipStream_t stream){
  const float* greek   = (const float*)d_in[0];
  const float* english = (const float*)d_in[1];
  const int*   labels  = (const int*)d_in[2];
  float* out = (float*)d_out;

  char* ws = (char*)d_ws;
  size_t off = 0;
  unsigned short* GposF = (unsigned short*)(ws + off); off += (size_t)BB*NTILES*TILE_BYTES; // 8MB
  unsigned short* EnegF = (unsigned short*)(ws + off); off += (size_t)BB*NTILES*TILE_BYTES; // 8MB
  float* Spart  = (float*)(ws + off); off += (size_t)BB*PP*8*sizeof(float);   // 512KB
  float* diagC  = (float*)(ws + off); off += (size_t)BB*PP*sizeof(float);     // 64KB
  int*   rank   = (int*)(ws + off);   off += (size_t)BB*PP*sizeof(int);       // 64KB
  int*   meta   = (int*)(ws + off);   off += 64;

  k_scan<<<BB, 256, 0, stream>>>(labels, meta, rank);
  k_norm<<<PP/4, 256, 0, stream>>>(greek, english, labels, rank, GposF, EnegF, diagC);
  k_loss<<<(PP/64)*32, 256, 0, stream>>>(GposF, EnegF, meta, Spart);
  k_final<<<1, 1024, 0, stream>>>(Spart, diagC, meta, out);
}

// Round 13
// 37.532 us; speedup vs baseline: 1.2285x; 1.0486x over previous
//
#include <hip/hip_runtime.h>
#include <hip/hip_bf16.h>
#include <math.h>

#define BB 4
#define PP 4096
#define HH 256
#define INV_T (1.0f/0.07f)
#define JSPLIT 8
#define NTILES (PP/16)
#define TILE_BYTES 8192

typedef __attribute__((ext_vector_type(8))) short bf16x8;
typedef __attribute__((ext_vector_type(4))) float f32x4;

#define WAITVM(n) asm volatile("s_waitcnt vmcnt(" #n ")" ::: "memory")

__device__ __forceinline__ unsigned short f2bf(float x){
  union { float f; unsigned u; } v; v.f = x;
  unsigned r = v.u + 0x7FFFu + ((v.u >> 16) & 1u);   // RNE
  return (unsigned short)(r >> 16);
}

__device__ __forceinline__ void gload_lds16(const void* g, void* l){
  __builtin_amdgcn_global_load_lds(
      (const __attribute__((address_space(1))) unsigned int*)g,
      (__attribute__((address_space(3))) unsigned int*)l, 16, 0, 0);
}

// ---------------- D1: fused scan+normalize -> frag-ready compacted tiles ----------------
// 1024 blocks; block B owns rows 4B..4B+3 (one per wave) in every batch.
// Rank base recomputed per block by scanning labels[0, r0) (L1/L2-hot, ~8 iters avg);
// in-block offsets from the 4 row labels. Block 1023 writes meta (valid==pos+neg here,
// so batch_ok <=> Np>0 && Nn>0). pos -> GposF frag-ready @rank + diagC[rank];
// neg -> EnegF frag-ready @rank. Unwritten tile slots stay garbage: rows >= Np are
// skipped in k_final, cols >= Nn masked in k_loss.
__global__ void k_prep(const float* __restrict__ greek, const float* __restrict__ english,
                       const int* __restrict__ labels,
                       unsigned short* __restrict__ GposF, unsigned short* __restrict__ EnegF,
                       float* __restrict__ diagC, int* __restrict__ meta){
  int tid = threadIdx.x, wave = tid >> 6, lane = tid & 63;
  int r0 = blockIdx.x * 4;
  __shared__ int redP[4], redN[4];
  __shared__ int rowLab[4];

  for (int b = 0; b < BB; b++){
    const int* lab = labels + b * PP;
    // block-wide count of pos/neg in [0, r0)
    int cp = 0, cn = 0;
    for (int j = tid; j < r0; j += 256){
      int l = lab[j];
      cp += (l == 1); cn += (l == 0);
    }
    #pragma unroll
    for (int off = 32; off; off >>= 1){ cp += __shfl_xor(cp, off); cn += __shfl_xor(cn, off); }
    if (lane == 0){ redP[wave] = cp; redN[wave] = cn; }
    if (tid < 4) rowLab[tid] = lab[r0 + tid];
    __syncthreads();
    int baseP = redP[0] + redP[1] + redP[2] + redP[3];
    int baseN = redN[0] + redN[1] + redN[2] + redN[3];
    int l0 = rowLab[0], l1 = rowLab[1], l2 = rowLab[2], l3 = rowLab[3];
    __syncthreads();   // reads done before next batch iteration overwrites LDS

    int myLab = (wave == 0) ? l0 : (wave == 1) ? l1 : (wave == 2) ? l2 : l3;
    int offP = 0, offN = 0;
    if (wave > 0){ offP += (l0 == 1); offN += (l0 == 0); }
    if (wave > 1){ offP += (l1 == 1); offN += (l1 == 0); }
    if (wave > 2){ offP += (l2 == 1); offN += (l2 == 0); }

    if (blockIdx.x == PP/4 - 1 && tid == 0){
      int Np = baseP + (l0==1)+(l1==1)+(l2==1)+(l3==1);
      int Nn = baseN + (l0==0)+(l1==0)+(l2==0)+(l3==0);
      meta[b*4+0] = Np; meta[b*4+1] = Nn;
      meta[b*4+2] = (Np > 0 && Nn > 0) ? 1 : 0;
      meta[b*4+3] = Np + Nn;
    }

    if (myLab == -100) continue;           // wave-uniform
    int u = b * PP + r0 + wave;
    size_t base = (size_t)u * HH + lane * 4;
    if (myLab == 1){
      int rk = baseP + offP;
      float4 g4 = *reinterpret_cast<const float4*>(greek + base);
      float4 e4 = *reinterpret_cast<const float4*>(english + base);
      float ag = g4.x*g4.x + g4.y*g4.y + g4.z*g4.z + g4.w*g4.w;
      float ae = e4.x*e4.x + e4.y*e4.y + e4.z*e4.z + e4.w*e4.w;
      float ad = g4.x*e4.x + g4.y*e4.y + g4.z*e4.z + g4.w*e4.w;
      #pragma unroll
      for (int off = 32; off; off >>= 1){
        ag += __shfl_xor(ag, off); ae += __shfl_xor(ae, off); ad += __shfl_xor(ad, off);
      }
      float gs = 1.0f / fmaxf(sqrtf(ag), 1e-12f);
      float es = 1.0f / fmaxf(sqrtf(ae), 1e-12f);
      unsigned u0 = (unsigned)f2bf(g4.x*gs) | ((unsigned)f2bf(g4.y*gs) << 16);
      unsigned u1 = (unsigned)f2bf(g4.z*gs) | ((unsigned)f2bf(g4.w*gs) << 16);
      unsigned o0 = __shfl_xor(u0, 1), o1 = __shfl_xor(u1, 1);
      char* dst = (char*)GposF + ((size_t)b*NTILES + (rk>>4))*TILE_BYTES
                + (lane>>3)*1024 + (((rk&15) + ((lane>>1)&3)*16) << 4);
      if (!(lane & 1)) *(uint4*)dst = make_uint4(u0, u1, o0, o1);
      if (lane == 0) diagC[b*PP + rk] = ad * gs * es;
    } else {   // myLab == 0: negative column
      int rk = baseN + offN;
      float4 e4 = *reinterpret_cast<const float4*>(english + base);
      float ae = e4.x*e4.x + e4.y*e4.y + e4.z*e4.z + e4.w*e4.w;
      #pragma unroll
      for (int off = 32; off; off >>= 1) ae += __shfl_xor(ae, off);
      float es = 1.0f / fmaxf(sqrtf(ae), 1e-12f);
      unsigned u0 = (unsigned)f2bf(e4.x*es) | ((unsigned)f2bf(e4.y*es) << 16);
      unsigned u1 = (unsigned)f2bf(e4.z*es) | ((unsigned)f2bf(e4.w*es) << 16);
      unsigned o0 = __shfl_xor(u0, 1), o1 = __shfl_xor(u1, 1);
      char* dst = (char*)EnegF + ((size_t)b*NTILES + (rk>>4))*TILE_BYTES
                + (lane>>3)*1024 + (((rk&15) + ((lane>>1)&3)*16) << 4);
      if (!(lane & 1)) *(uint4*)dst = make_uint4(u0, u1, o0, o1);
    }
  }
}

// ---------------- D2: MFMA exp-sums (r5-verified loop, contiguous frag-ready A) ----------------
// 1-D grid 2048, L = rb*32 + (b*8+chunk) -> B-slice XCD locality.
__global__ void __launch_bounds__(256, 4)
k_loss(const unsigned short* __restrict__ GposF,
       const unsigned short* __restrict__ EnegF,
       const int* __restrict__ meta,
       float* __restrict__ Spart){
  int L = blockIdx.x;
  int rb = L >> 5;
  int pair = L & 31;
  int b = pair >> 3, chunk = pair & 7;
  int Np = meta[b*4+0], Nn = meta[b*4+1], ok = meta[b*4+2];
  int i0 = rb * 64;
  if (!ok || i0 >= Np) return;
  int tid = threadIdx.x, wave = tid >> 6, lane = tid & 63;
  int lo16 = lane & 15, hi4 = lane >> 4;
  int NT = (Nn + 15) >> 4;
  int TPC = (NT + JSPLIT - 1) / JSPLIT;
  int t0 = chunk * TPC, t1 = min(NT, t0 + TPC);

  __shared__ __align__(16) char Bs[3][TILE_BYTES];   // 24 KB triple buffer

  // A fragments (one-time, fully coalesced)
  const char* AF = (const char*)GposF + ((size_t)b*NTILES + (i0 >> 4) + wave) * TILE_BYTES;
  bf16x8 a[8];
  #pragma unroll
  for (int kk = 0; kk < 8; kk++)
    a[kk] = *reinterpret_cast<const bf16x8*>(AF + kk*1024 + (lane << 4));

  const char* EF = (const char*)EnegF + (size_t)b * NTILES * TILE_BYTES;
  float s[4] = {0.f, 0.f, 0.f, 0.f};

  if (t0 < t1){
    {
      const char* src = EF + (size_t)t0*TILE_BYTES + (wave << 11) + (lane << 4);
      char* dstl = &Bs[0][wave << 11];
      gload_lds16(src, dstl);
      gload_lds16(src + 1024, dstl + 1024);
    }
    if (t0 + 1 < t1){
      const char* src = EF + (size_t)(t0+1)*TILE_BYTES + (wave << 11) + (lane << 4);
      char* dstl = &Bs[1][wave << 11];
      gload_lds16(src, dstl);
      gload_lds16(src + 1024, dstl + 1024);
    }
    int cur = 0;
    for (int t = t0; t < t1; t++){
      if (t + 1 < t1) WAITVM(2);
      else            WAITVM(0);
      __builtin_amdgcn_s_barrier();
      __builtin_amdgcn_sched_barrier(0);

      if (t + 2 < t1){
        int nb = cur + 2; if (nb >= 3) nb -= 3;
        const char* src = EF + (size_t)(t+2)*TILE_BYTES + (wave << 11) + (lane << 4);
        char* dstl = &Bs[nb][wave << 11];
        gload_lds16(src, dstl);
        gload_lds16(src + 1024, dstl + 1024);
      }

      const char* Bt = &Bs[cur][0];
      f32x4 c = {0.f, 0.f, 0.f, 0.f};
      #pragma unroll
      for (int kk = 0; kk < 8; kk++){
        bf16x8 bv = *reinterpret_cast<const bf16x8*>(Bt + kk*1024 + (lane << 4));
        c = __builtin_amdgcn_mfma_f32_16x16x32_bf16(a[kk], bv, c, 0, 0, 0);
      }
      bool cok = (t*16 + lo16) < Nn;
      #pragma unroll
      for (int r = 0; r < 4; r++)
        s[r] += cok ? __expf(c[r] * INV_T) : 0.0f;

      cur = (cur == 2) ? 0 : cur + 1;
    }
  }

  // reduce across the 16 col-lanes; D layout: col=lane&15, row=hi4*4+r
  #pragma unroll
  for (int off = 1; off < 16; off <<= 1){
    #pragma unroll
    for (int r = 0; r < 4; r++) s[r] += __shfl_xor(s[r], off);
  }
  if (lo16 == 0){
    #pragma unroll
    for (int r = 0; r < 4; r++){
      int i = i0 + wave*16 + hi4*4 + r;
      Spart[(((size_t)b*PP + i) << 3) + chunk] = s[r];
    }
  }
}

// ---------------- D3: fold partials -> per-row loss -> mean ----------------
__global__ void k_final(const float* __restrict__ Spart, const float* __restrict__ diagC,
                        const int* __restrict__ meta, float* __restrict__ out){
  __shared__ float lds[16];
  int tid = threadIdx.x;
  int np[BB], okk[BB];
  #pragma unroll
  for (int b = 0; b < BB; b++){ np[b] = meta[b*4+0]; okk[b] = meta[b*4+2]; }
  float tot = 0.0f;
  for (int idx = tid; idx < BB*PP; idx += 1024){
    int b = idx >> 12, i = idx & (PP-1);
    if (!okk[b] || i >= np[b]) continue;
    const float4* p = reinterpret_cast<const float4*>(Spart + ((size_t)idx << 3));
    float4 p0 = p[0], p1 = p[1];
    float S = ((p0.x+p0.y)+(p0.z+p0.w)) + ((p1.x+p1.y)+(p1.z+p1.w));
    float dl = diagC[idx] * INV_T;
    tot += logf(S + __expf(dl)) - dl;
  }
  #pragma unroll
  for (int off = 32; off; off >>= 1) tot += __shfl_xor(tot, off);
  int wave = tid >> 6;
  if ((tid & 63) == 0) lds[wave] = tot;
  __syncthreads();
  if (tid == 0){
    float total = 0.0f;
    #pragma unroll
    for (int w = 0; w < 16; w++) total += lds[w];
    int count = 0;
    #pragma unroll
    for (int b = 0; b < BB; b++) if (okk[b]) count += np[b];
    out[0] = (count == 0) ? 0.0f : total / (float)count;
  }
}

extern "C" void kernel_launch(void* const* d_in, const int* in_sizes, int n_in,
                              void* d_out, int out_size, void* d_ws, size_t ws_size,
                              hipStream_t stream){
  const float* greek   = (const float*)d_in[0];
  const float* english = (const float*)d_in[1];
  const int*   labels  = (const int*)d_in[2];
  float* out = (float*)d_out;

  char* ws = (char*)d_ws;
  size_t off = 0;
  unsigned short* GposF = (unsigned short*)(ws + off); off += (size_t)BB*NTILES*TILE_BYTES; // 8MB
  unsigned short* EnegF = (unsigned short*)(ws + off); off += (size_t)BB*NTILES*TILE_BYTES; // 8MB
  float* Spart  = (float*)(ws + off); off += (size_t)BB*PP*8*sizeof(float);   // 512KB
  float* diagC  = (float*)(ws + off); off += (size_t)BB*PP*sizeof(float);     // 64KB
  int*   meta   = (int*)(ws + off);   off += 64;

  k_prep<<<PP/4, 256, 0, stream>>>(greek, english, labels, GposF, EnegF, diagC, meta);
  k_loss<<<(PP/64)*32, 256, 0, stream>>>(GposF, EnegF, meta, Spart);
  k_final<<<1, 1024, 0, stream>>>(Spart, diagC, meta, out);
}